// Round 1
// baseline (3333.906 us; speedup 1.0000x reference)
//
#include <hip/hip_runtime.h>

// LSTM_8650064134553 : 2-layer stacked LSTM, B=32768, D=128, H=64, 32 steps.
// Round 1: fp32 vector baseline. Persistent block per 64-row batch tile,
// state lives in LDS/registers across all 32 steps (batch rows independent).
// Weights pre-transposed into d_ws so gate-weight loads are lane-coalesced.

#define B_     32768
#define D_     128
#define H_     64
#define NSTEP_ 32
#define G4H_   256           // 4*H
#define K0_    192           // D + H   (layer0 input  = [y | h0])
#define K1_    128           // H + H   (layer1 input  = [h0 | h1])
#define ROWS_  64            // batch rows per block
#define NTHR_  256
#define NBLK_  (B_ / ROWS_)  // 512

__device__ __forceinline__ float fsig(float x) {
  // sigmoid(x) = 1 / (1 + 2^(-x*log2e))
  float e = __builtin_amdgcn_exp2f(-1.44269504088896f * x);
  return __builtin_amdgcn_rcpf(1.0f + e);
}
__device__ __forceinline__ float ftanh(float x) {
  // tanh(x) = 1 - 2/(e^(2x)+1)
  float e = __builtin_amdgcn_exp2f(2.88539008177793f * x);
  return 1.0f - 2.0f * __builtin_amdgcn_rcpf(e + 1.0f);
}

// One half of a gate GEMM: acc[g][i] += act[rbase+i][k] * Wt[k][g*64+c]
// act reads are wave-uniform (broadcast, conflict-free); weight reads are
// lane-coalesced (c = lane id).
__device__ __forceinline__ void gemm_part(const float* __restrict__ Wt,
                                          const float* __restrict__ act,
                                          int stride, int klen, int c,
                                          float acc[4][16]) {
#pragma unroll 2
  for (int k = 0; k < klen; k += 2) {
    float2 a[16];
#pragma unroll
    for (int i = 0; i < 16; ++i)
      a[i] = *(const float2*)(act + i * stride + k);
    const float* w = Wt + k * G4H_ + c;
#pragma unroll
    for (int kk = 0; kk < 2; ++kk) {
      float wi = w[kk * G4H_];
      float wf = w[kk * G4H_ + 64];
      float wg = w[kk * G4H_ + 128];
      float wo = w[kk * G4H_ + 192];
#pragma unroll
      for (int i = 0; i < 16; ++i) {
        float av = kk ? a[i].y : a[i].x;
        acc[0][i] = fmaf(av, wi, acc[0][i]);
        acc[1][i] = fmaf(av, wf, acc[1][i]);
        acc[2][i] = fmaf(av, wg, acc[2][i]);
        acc[3][i] = fmaf(av, wo, acc[3][i]);
      }
    }
  }
}

// Transpose/concat weights into ws:
//   Wt0 [192][256] = [Wih0^T ; Whh0^T]
//   Wt1 [128][256] = [Wih1^T ; Whh1^T]
//   Wtfc [64][128] = Wfc^T
__global__ void prep_w(const float* __restrict__ Wih0,
                       const float* __restrict__ Whh0,
                       const float* __restrict__ Wih1,
                       const float* __restrict__ Whh1,
                       const float* __restrict__ Wfc,
                       float* __restrict__ ws) {
  int idx = blockIdx.x * blockDim.x + threadIdx.x;
  int np  = gridDim.x * blockDim.x;
  float* Wt0  = ws;
  float* Wt1  = ws + K0_ * G4H_;
  float* Wtfc = ws + (K0_ + K1_) * G4H_;
  for (int i = idx; i < K0_ * G4H_; i += np) {
    int k = i >> 8, j = i & 255;
    Wt0[i] = (k < D_) ? Wih0[j * D_ + k] : Whh0[j * H_ + (k - D_)];
  }
  for (int i = idx; i < K1_ * G4H_; i += np) {
    int k = i >> 8, j = i & 255;
    Wt1[i] = (k < H_) ? Wih1[j * H_ + k] : Whh1[j * H_ + (k - H_)];
  }
  for (int i = idx; i < H_ * D_; i += np) {
    int k = i >> 7, d = i & 127;
    Wtfc[i] = Wfc[d * H_ + k];
  }
}

__global__ __launch_bounds__(NTHR_, 2)
void lstm_fused(const float* __restrict__ x,
                const float* __restrict__ b0,
                const float* __restrict__ b1,
                const float* __restrict__ bfc,
                const float* __restrict__ ws,
                float* __restrict__ out) {
  __shared__ float s_in[ROWS_][D_];   // 32 KB: current step input (x, then y)
  __shared__ float s_h0[ROWS_][H_];   // 16 KB
  __shared__ float s_h1[ROWS_][H_];   // 16 KB  (total 64 KB -> 2 blocks/CU)

  const float* Wt0  = ws;
  const float* Wt1  = ws + K0_ * G4H_;
  const float* Wtfc = ws + (K0_ + K1_) * G4H_;

  const int tid   = threadIdx.x;
  const int c     = tid & 63;    // cell / output column within 64-group (lane id)
  const int rg    = tid >> 6;    // wave id -> row group
  const int rbase = rg * 16;     // this thread covers rows rbase..rbase+15
  const int row0  = blockIdx.x * ROWS_;

  // biases (constant across steps)
  const float bi0 = b0[c], bf0 = b0[64 + c], bg0 = b0[128 + c], bo0 = b0[192 + c];
  const float bi1 = b1[c], bf1 = b1[64 + c], bg1 = b1[128 + c], bo1 = b1[192 + c];
  const float by0 = bfc[c], by1 = bfc[64 + c];

  // cell state in registers: c-state for (row rbase+i, cell c), both layers
  float c0s[16], c1s[16];
#pragma unroll
  for (int i = 0; i < 16; ++i) { c0s[i] = 0.0f; c1s[i] = 0.0f; }

  for (int i = tid; i < ROWS_ * H_; i += NTHR_) {
    (&s_h0[0][0])[i] = 0.0f;
    (&s_h1[0][0])[i] = 0.0f;
  }
  for (int i = tid; i < ROWS_ * D_; i += NTHR_)
    (&s_in[0][0])[i] = x[(size_t)row0 * D_ + i];
  __syncthreads();

  for (int t = 0; t < NSTEP_; ++t) {
    // ---------------- layer 0: gates = [s_in | s_h0] @ Wt0 ----------------
    float acc0[4][16];
#pragma unroll
    for (int g = 0; g < 4; ++g)
#pragma unroll
      for (int i = 0; i < 16; ++i) acc0[g][i] = 0.0f;

    gemm_part(Wt0,              &s_in[rbase][0], D_, D_, c, acc0);
    gemm_part(Wt0 + D_ * G4H_,  &s_h0[rbase][0], H_, H_, c, acc0);
    __syncthreads();  // everyone done reading old s_h0

#pragma unroll
    for (int i = 0; i < 16; ++i) {
      float ig = fsig (acc0[0][i] + bi0);
      float fg = fsig (acc0[1][i] + bf0);
      float gg = ftanh(acc0[2][i] + bg0);
      float og = fsig (acc0[3][i] + bo0);
      float cn = fmaf(fg, c0s[i], ig * gg);
      c0s[i] = cn;
      s_h0[rbase + i][c] = og * ftanh(cn);
    }
    __syncthreads();  // new h0 visible

    // ---------------- layer 1: gates = [s_h0 | s_h1] @ Wt1 ----------------
    float acc1[4][16];
#pragma unroll
    for (int g = 0; g < 4; ++g)
#pragma unroll
      for (int i = 0; i < 16; ++i) acc1[g][i] = 0.0f;

    gemm_part(Wt1,              &s_h0[rbase][0], H_, H_, c, acc1);
    gemm_part(Wt1 + H_ * G4H_,  &s_h1[rbase][0], H_, H_, c, acc1);
    __syncthreads();  // everyone done reading old s_h1

#pragma unroll
    for (int i = 0; i < 16; ++i) {
      float ig = fsig (acc1[0][i] + bi1);
      float fg = fsig (acc1[1][i] + bf1);
      float gg = ftanh(acc1[2][i] + bg1);
      float og = fsig (acc1[3][i] + bo1);
      float cn = fmaf(fg, c1s[i], ig * gg);
      c1s[i] = cn;
      s_h1[rbase + i][c] = og * ftanh(cn);
    }
    __syncthreads();  // new h1 visible

    // ---------------- fc: y = s_h1 @ Wtfc + bfc ----------------
    // thread covers output dims {c, 64+c} for rows rbase..rbase+15
    float ay0[16], ay1[16];
#pragma unroll
    for (int i = 0; i < 16; ++i) { ay0[i] = 0.0f; ay1[i] = 0.0f; }

#pragma unroll 2
    for (int k = 0; k < H_; k += 2) {
      float2 a[16];
#pragma unroll
      for (int i = 0; i < 16; ++i)
        a[i] = *(const float2*)(&s_h1[rbase + i][k]);
#pragma unroll
      for (int kk = 0; kk < 2; ++kk) {
        float w0 = Wtfc[(k + kk) * D_ + c];
        float w1 = Wtfc[(k + kk) * D_ + 64 + c];
#pragma unroll
        for (int i = 0; i < 16; ++i) {
          float av = kk ? a[i].y : a[i].x;
          ay0[i] = fmaf(av, w0, ay0[i]);
          ay1[i] = fmaf(av, w1, ay1[i]);
        }
      }
    }

    // out layout: [ y_last (B*D) | y_stack (NSTEP*B*D) ]
    const size_t obase = (size_t)(t + 1) * B_ * D_ + (size_t)row0 * D_;
#pragma unroll
    for (int i = 0; i < 16; ++i) {
      int   r   = rbase + i;
      float y0v = ay0[i] + by0;
      float y1v = ay1[i] + by1;
      s_in[r][c]      = y0v;   // feed back as next-step input
      s_in[r][64 + c] = y1v;
      out[obase + (size_t)r * D_ + c]      = y0v;
      out[obase + (size_t)r * D_ + 64 + c] = y1v;
      if (t == NSTEP_ - 1) {
        out[(size_t)(row0 + r) * D_ + c]      = y0v;
        out[(size_t)(row0 + r) * D_ + 64 + c] = y1v;
      }
    }
    __syncthreads();  // s_in ready for next step's layer-0 GEMM
  }
}

extern "C" void kernel_launch(void* const* d_in, const int* in_sizes, int n_in,
                              void* d_out, int out_size, void* d_ws, size_t ws_size,
                              hipStream_t stream) {
  const float* x    = (const float*)d_in[0];
  const float* Wih0 = (const float*)d_in[1];
  const float* Whh0 = (const float*)d_in[2];
  const float* b0   = (const float*)d_in[3];
  const float* Wih1 = (const float*)d_in[4];
  const float* Whh1 = (const float*)d_in[5];
  const float* b1   = (const float*)d_in[6];
  const float* Wfc  = (const float*)d_in[7];
  const float* bfc  = (const float*)d_in[8];
  float* ws  = (float*)d_ws;
  float* out = (float*)d_out;

  prep_w<<<64, NTHR_, 0, stream>>>(Wih0, Whh0, Wih1, Whh1, Wfc, ws);
  lstm_fused<<<NBLK_, NTHR_, 0, stream>>>(x, b0, b1, bfc, ws, out);
}